// Round 2
// baseline (2176.386 us; speedup 1.0000x reference)
//
#include <hip/hip_runtime.h>

#define BATCH   16
#define NPTS    4096
#define NPOINT  1024
#define NSAMPLE 32

// ---------------------------------------------------------------------------
// Kernel 1: farthest point sampling. One block per batch, 512 threads,
// 8 points per thread held in registers. Exact numpy fp32 op order:
// d = ((dx*dx + dy*dy) + dz*dz), dist = min(dist, d), argmax = first max.
// Writes new_xyz (the gathered centroids) directly to d_out.
// VALIDATED bit-exact in round 1 — do not change arithmetic.
// ---------------------------------------------------------------------------
__global__ __launch_bounds__(512)
void fps_kernel(const float* __restrict__ xyz, float* __restrict__ new_xyz)
{
    const int b = blockIdx.x;
    const int t = threadIdx.x;
    const float* xb = xyz + (size_t)b * NPTS * 3;

    float px[8], py[8], pz[8], dist[8];
#pragma unroll
    for (int j = 0; j < 8; ++j) {
        int n = j * 512 + t;
        px[j] = xb[n * 3 + 0];
        py[j] = xb[n * 3 + 1];
        pz[j] = xb[n * 3 + 2];
        dist[j] = 1e10f;
    }

    __shared__ float sVal[8], sCx[8], sCy[8], sCz[8];
    __shared__ int   sIdx[8];
    __shared__ float sC[3];

    if (t == 0) { sC[0] = px[0]; sC[1] = py[0]; sC[2] = pz[0]; }
    __syncthreads();
    float cx = sC[0], cy = sC[1], cz = sC[2];

    float* out = new_xyz + (size_t)b * NPOINT * 3;

    for (int i = 0; i < NPOINT; ++i) {
        if (t == 0) { out[i*3+0] = cx; out[i*3+1] = cy; out[i*3+2] = cz; }

        // update running min-distances, track per-thread argmax (first max)
        float bval = -1.0f; int bidx = 0x7fffffff;
        float bx = 0.f, by = 0.f, bz = 0.f;
#pragma unroll
        for (int j = 0; j < 8; ++j) {
            float dx = __fsub_rn(px[j], cx);
            float dy = __fsub_rn(py[j], cy);
            float dz = __fsub_rn(pz[j], cz);
            float d  = __fadd_rn(__fadd_rn(__fmul_rn(dx, dx), __fmul_rn(dy, dy)),
                                 __fmul_rn(dz, dz));
            float nd = fminf(dist[j], d);
            dist[j] = nd;
            // per-thread n ascending in j, so strict > keeps first occurrence
            if (nd > bval) { bval = nd; bidx = j * 512 + t; bx = px[j]; by = py[j]; bz = pz[j]; }
        }

        // wave (64-lane) argmax reduce, tie -> smaller global index
#pragma unroll
        for (int off = 32; off >= 1; off >>= 1) {
            float ov = __shfl_xor(bval, off);
            int   oi = __shfl_xor(bidx, off);
            float ox = __shfl_xor(bx, off);
            float oy = __shfl_xor(by, off);
            float oz = __shfl_xor(bz, off);
            if (ov > bval || (ov == bval && oi < bidx)) {
                bval = ov; bidx = oi; bx = ox; by = oy; bz = oz;
            }
        }
        int w = t >> 6;
        if ((t & 63) == 0) { sVal[w] = bval; sIdx[w] = bidx; sCx[w] = bx; sCy[w] = by; sCz[w] = bz; }
        __syncthreads();
        if (t == 0) {
            float v = sVal[0]; int ix = sIdx[0];
            float X = sCx[0], Y = sCy[0], Z = sCz[0];
#pragma unroll
            for (int u = 1; u < 8; ++u) {
                float uv = sVal[u]; int ui = sIdx[u];
                if (uv > v || (uv == v && ui < ix)) { v = uv; ix = ui; X = sCx[u]; Y = sCy[u]; Z = sCz[u]; }
            }
            sC[0] = X; sC[1] = Y; sC[2] = Z;
        }
        __syncthreads();
        cx = sC[0]; cy = sC[1]; cz = sC[2];
    }
}

// ---------------------------------------------------------------------------
// Kernel 2: ball query. One wave per query point. Scans points in ascending
// index order, takes the first 32 with d2 <= r^2, pads with first in-ball idx.
// d2 arithmetic must match numpy: dot via SEQUENTIAL FMA (einsum inner loop
// contracts to fma), everything else separate _rn ops (distinct ufuncs).
// ---------------------------------------------------------------------------
__global__ __launch_bounds__(256)
void ball_kernel(const float* __restrict__ xyz, const float* __restrict__ new_xyz,
                 int* __restrict__ idx)
{
    const int q    = blockIdx.x * 4 + (threadIdx.x >> 6);
    const int lane = threadIdx.x & 63;
    const int b    = q >> 10;
    const float* xb = xyz + (size_t)b * NPTS * 3;

    const float s0 = new_xyz[q*3+0];
    const float s1 = new_xyz[q*3+1];
    const float s2 = new_xyz[q*3+2];
    // np.sum(new**2, -1): separate square + sequential add ufuncs -> plain _rn
    const float ssum = __fadd_rn(__fadd_rn(__fmul_rn(s0,s0), __fmul_rn(s1,s1)),
                                 __fmul_rn(s2,s2));
    const float r2 = (float)(0.2 * 0.2);

    int* myidx = idx + (size_t)q * NSAMPLE;
    int found = 0;
    int first = -1;

    for (int c = 0; c < NPTS / 64 && found < NSAMPLE; ++c) {
        int n = c * 64 + lane;
        float x = xb[n*3+0], y = xb[n*3+1], z = xb[n*3+2];
        float nsum = __fadd_rn(__fadd_rn(__fmul_rn(x,x), __fmul_rn(y,y)), __fmul_rn(z,z));
        // einsum dot: accum starts at 0, sequential FMA over c
        float dot  = __fmaf_rn(s2, z, __fmaf_rn(s1, y, __fmul_rn(s0, x)));
        // d2 = (ssum + nsum) - 2*dot, each a separate rn op; 2*dot exact
        float d2   = __fsub_rn(__fadd_rn(ssum, nsum), __fmul_rn(2.0f, dot));
        bool inb = !(d2 > r2);
        unsigned long long m = __ballot(inb);
        if (first < 0 && m != 0ull) first = c * 64 + (int)__builtin_ctzll(m);
        if (inb) {
            int rank = __popcll(m & ((1ull << lane) - 1ull));
            int slot = found + rank;
            if (slot < NSAMPLE) myidx[slot] = n;
        }
        found += __popcll(m);
    }
    if (found > NSAMPLE) found = NSAMPLE;
    for (int slot = found + lane; slot < NSAMPLE; slot += 64) myidx[slot] = first;
}

// ---------------------------------------------------------------------------
// Kernel 3: gather + 3x (matmul, BN, ReLU) + max over the 32 samples.
// BN folded into weights/bias. Weights staged transposed in LDS, read as
// broadcast float4 (conflict-free). Lane = (s_local*32 + k): max-pool is a
// 32-lane shfl_xor reduce. One point per lane. Continuous math -> fp32 noise
// only, far below threshold.
// ---------------------------------------------------------------------------
__global__ __launch_bounds__(256)
void mlp_kernel(const float* __restrict__ xyz, const float* __restrict__ points,
                const float* __restrict__ new_xyz, const int* __restrict__ idx,
                const float* __restrict__ W1, const float* __restrict__ g1,
                const float* __restrict__ b1, const float* __restrict__ m1,
                const float* __restrict__ v1,
                const float* __restrict__ W2, const float* __restrict__ g2,
                const float* __restrict__ b2, const float* __restrict__ m2,
                const float* __restrict__ v2,
                const float* __restrict__ W3, const float* __restrict__ g3,
                const float* __restrict__ b3, const float* __restrict__ m3,
                const float* __restrict__ v3,
                float* __restrict__ feat)
{
    __shared__ float w1t[64][8];     // [out][in(6, padded 8)]
    __shared__ float w2t[64][64];    // [out][in]
    __shared__ float w3t[128][64];   // [out][in]
    __shared__ float bias1s[64], bias2s[64], bias3s[128];
    __shared__ float sc1[64], sc2[64], sc3[128];

    const int tid = threadIdx.x;

    for (int d = tid; d < 64; d += 256) {
        float s1v = g1[d] / sqrtf(v1[d] + 1e-5f);
        sc1[d] = s1v; bias1s[d] = b1[d] - m1[d] * s1v;
        float s2v = g2[d] / sqrtf(v2[d] + 1e-5f);
        sc2[d] = s2v; bias2s[d] = b2[d] - m2[d] * s2v;
    }
    for (int d = tid; d < 128; d += 256) {
        float s3v = g3[d] / sqrtf(v3[d] + 1e-5f);
        sc3[d] = s3v; bias3s[d] = b3[d] - m3[d] * s3v;
    }
    __syncthreads();
    for (int e = tid; e < 64 * 8; e += 256) {
        int d = e >> 3, c = e & 7;
        w1t[d][c] = (c < 6) ? W1[c * 64 + d] * sc1[d] : 0.f;
    }
    for (int e = tid; e < 64 * 64; e += 256) {
        int d = e >> 6, c = e & 63;
        w2t[d][c] = W2[c * 64 + d] * sc2[d];
    }
    for (int e = tid; e < 128 * 64; e += 256) {
        int d = e >> 6, c = e & 63;
        w3t[d][c] = W3[c * 128 + d] * sc3[d];
    }
    __syncthreads();

    const int wid  = tid >> 6;
    const int lane = tid & 63;
    const int q = blockIdx.x * 8 + wid * 2 + (lane >> 5);
    const int k = lane & 31;
    const int b = q >> 10;

    const int n = idx[(size_t)q * NSAMPLE + k];
    const float* xp = xyz    + ((size_t)b * NPTS + n) * 3;
    const float* pp = points + ((size_t)b * NPTS + n) * 3;
    const float* nx = new_xyz + (size_t)q * 3;

    const float in0 = __fsub_rn(xp[0], nx[0]);
    const float in1 = __fsub_rn(xp[1], nx[1]);
    const float in2 = __fsub_rn(xp[2], nx[2]);
    const float in3 = pp[0], in4 = pp[1], in5 = pp[2];

    float x1[64];
#pragma unroll
    for (int d = 0; d < 64; ++d) {
        const float4 wa = *(const float4*)&w1t[d][0];
        const float4 wb = *(const float4*)&w1t[d][4];
        float acc = bias1s[d];
        acc = fmaf(in0, wa.x, acc);
        acc = fmaf(in1, wa.y, acc);
        acc = fmaf(in2, wa.z, acc);
        acc = fmaf(in3, wa.w, acc);
        acc = fmaf(in4, wb.x, acc);
        acc = fmaf(in5, wb.y, acc);
        x1[d] = fmaxf(acc, 0.f);
    }

    float x2[64];
#pragma unroll
    for (int d = 0; d < 64; ++d) {
        float acc = bias2s[d];
        const float4* wr = (const float4*)w2t[d];
#pragma unroll
        for (int cc = 0; cc < 16; ++cc) {
            float4 w = wr[cc];
            acc = fmaf(x1[4*cc+0], w.x, acc);
            acc = fmaf(x1[4*cc+1], w.y, acc);
            acc = fmaf(x1[4*cc+2], w.z, acc);
            acc = fmaf(x1[4*cc+3], w.w, acc);
        }
        x2[d] = fmaxf(acc, 0.f);
    }

    float* fq = feat + (size_t)q * 128;
    for (int d = 0; d < 128; ++d) {
        float acc = bias3s[d];
        const float4* wr = (const float4*)w3t[d];
#pragma unroll
        for (int cc = 0; cc < 16; ++cc) {
            float4 w = wr[cc];
            acc = fmaf(x2[4*cc+0], w.x, acc);
            acc = fmaf(x2[4*cc+1], w.y, acc);
            acc = fmaf(x2[4*cc+2], w.z, acc);
            acc = fmaf(x2[4*cc+3], w.w, acc);
        }
        float vv = fmaxf(acc, 0.f);
#pragma unroll
        for (int off = 16; off >= 1; off >>= 1)
            vv = fmaxf(vv, __shfl_xor(vv, off));
        if (k == 0) fq[d] = vv;
    }
}

extern "C" void kernel_launch(void* const* d_in, const int* in_sizes, int n_in,
                              void* d_out, int out_size, void* d_ws, size_t ws_size,
                              hipStream_t stream)
{
    (void)in_sizes; (void)n_in; (void)out_size; (void)ws_size;

    const float* xyz    = (const float*)d_in[0];
    const float* points = (const float*)d_in[1];
    const float* W1 = (const float*)d_in[2];
    const float* g1 = (const float*)d_in[3];
    const float* b1 = (const float*)d_in[4];
    const float* m1 = (const float*)d_in[5];
    const float* v1 = (const float*)d_in[6];
    const float* W2 = (const float*)d_in[7];
    const float* g2 = (const float*)d_in[8];
    const float* b2 = (const float*)d_in[9];
    const float* m2 = (const float*)d_in[10];
    const float* v2 = (const float*)d_in[11];
    const float* W3 = (const float*)d_in[12];
    const float* g3 = (const float*)d_in[13];
    const float* b3 = (const float*)d_in[14];
    const float* m3 = (const float*)d_in[15];
    const float* v3 = (const float*)d_in[16];

    float* out_f    = (float*)d_out;
    float* new_xyz  = out_f;                                  // B*NPOINT*3
    float* feat     = out_f + (size_t)BATCH * NPOINT * 3;     // B*NPOINT*128
    int*   idx      = (int*)d_ws;                             // B*NPOINT*NSAMPLE ints

    fps_kernel <<<BATCH, 512, 0, stream>>>(xyz, new_xyz);
    ball_kernel<<<(BATCH * NPOINT) / 4, 256, 0, stream>>>(xyz, new_xyz, idx);
    mlp_kernel <<<(BATCH * NPOINT) / 8, 256, 0, stream>>>(xyz, points, new_xyz, idx,
        W1, g1, b1, m1, v1, W2, g2, b2, m2, v2, W3, g3, b3, m3, v3, feat);
}

// Round 3
// 1468.651 us; speedup vs baseline: 1.4819x; 1.4819x over previous
//
#include <hip/hip_runtime.h>

#define BATCH   16
#define NPTS    4096
#define NPOINT  1024
#define NSAMPLE 32

// ---------------------------------------------------------------------------
// Kernel 1: farthest point sampling. One block per batch, 256 threads
// (4 waves), 16 points per thread in registers. Exact numpy fp32 op order:
// d = ((dx*dx + dy*dy) + dz*dz), dist = min(dist, d), argmax = first max.
// Sync cost per iteration minimized: 12-shuffle (val,idx) butterfly,
// ONE __syncthreads with double-buffered 4-slot combine, winner coords
// fetched from an LDS copy of the point cloud (broadcast read).
// ---------------------------------------------------------------------------
__global__ __launch_bounds__(256)
void fps_kernel(const float* __restrict__ xyz, float* __restrict__ new_xyz)
{
    const int b    = blockIdx.x;
    const int t    = threadIdx.x;
    const int lane = t & 63;
    const int wv   = t >> 6;
    const float* xb = xyz + (size_t)b * NPTS * 3;

    __shared__ float sxyz[NPTS * 3];      // 48 KB point-cloud copy
    __shared__ float sVal[2][4];
    __shared__ int   sIdx[2][4];

    float px[16], py[16], pz[16], dist[16];
#pragma unroll
    for (int j = 0; j < 16; ++j) {
        const int n = j * 256 + t;
        const float X = xb[n * 3 + 0];
        const float Y = xb[n * 3 + 1];
        const float Z = xb[n * 3 + 2];
        px[j] = X; py[j] = Y; pz[j] = Z; dist[j] = 1e10f;
        sxyz[n * 3 + 0] = X; sxyz[n * 3 + 1] = Y; sxyz[n * 3 + 2] = Z;
    }
    __syncthreads();

    float cx = sxyz[0], cy = sxyz[1], cz = sxyz[2];   // first centroid = point 0
    float* out = new_xyz + (size_t)b * NPOINT * 3;

    for (int i = 0; i < NPOINT; ++i) {
        if (t == 0) { out[i*3+0] = cx; out[i*3+1] = cy; out[i*3+2] = cz; }

        // update running min-distances, track per-thread argmax (first max:
        // per-thread n ascends with j, so strict > keeps first occurrence)
        float bval = -1.0f; int bidx = 0x7fffffff;
#pragma unroll
        for (int j = 0; j < 16; ++j) {
            float dx = __fsub_rn(px[j], cx);
            float dy = __fsub_rn(py[j], cy);
            float dz = __fsub_rn(pz[j], cz);
            float d  = __fadd_rn(__fadd_rn(__fmul_rn(dx, dx), __fmul_rn(dy, dy)),
                                 __fmul_rn(dz, dz));
            float nd = fminf(dist[j], d);
            dist[j] = nd;
            if (nd > bval) { bval = nd; bidx = j * 256 + t; }
        }

        // wave argmax butterfly, tie -> smaller global index
#pragma unroll
        for (int off = 32; off >= 1; off >>= 1) {
            float ov = __shfl_xor(bval, off);
            int   oi = __shfl_xor(bidx, off);
            if (ov > bval || (ov == bval && oi < bidx)) { bval = ov; bidx = oi; }
        }

        // cross-wave combine: 4 candidates, double-buffered, single barrier
        const int par = i & 1;
        if (lane == 0) { sVal[par][wv] = bval; sIdx[par][wv] = bidx; }
        __syncthreads();
        float v = sVal[par][0]; int ix = sIdx[par][0];
#pragma unroll
        for (int u = 1; u < 4; ++u) {
            float uv = sVal[par][u]; int ui = sIdx[par][u];
            if (uv > v || (uv == v && ui < ix)) { v = uv; ix = ui; }
        }

        // winner coords via LDS broadcast read
        cx = sxyz[ix * 3 + 0];
        cy = sxyz[ix * 3 + 1];
        cz = sxyz[ix * 3 + 2];
    }
}

// ---------------------------------------------------------------------------
// Kernel 2: ball query. One wave per query point. Scans points in ascending
// index order, takes the first 32 with d2 <= r^2, pads with first in-ball idx.
// d2 arithmetic must match numpy: dot via SEQUENTIAL FMA (einsum inner loop
// contracts to fma), everything else separate _rn ops (distinct ufuncs).
// VALIDATED in round 2 — do not change arithmetic.
// ---------------------------------------------------------------------------
__global__ __launch_bounds__(256)
void ball_kernel(const float* __restrict__ xyz, const float* __restrict__ new_xyz,
                 int* __restrict__ idx)
{
    const int q    = blockIdx.x * 4 + (threadIdx.x >> 6);
    const int lane = threadIdx.x & 63;
    const int b    = q >> 10;
    const float* xb = xyz + (size_t)b * NPTS * 3;

    const float s0 = new_xyz[q*3+0];
    const float s1 = new_xyz[q*3+1];
    const float s2 = new_xyz[q*3+2];
    const float ssum = __fadd_rn(__fadd_rn(__fmul_rn(s0,s0), __fmul_rn(s1,s1)),
                                 __fmul_rn(s2,s2));
    const float r2 = (float)(0.2 * 0.2);

    int* myidx = idx + (size_t)q * NSAMPLE;
    int found = 0;
    int first = -1;

    for (int c = 0; c < NPTS / 64 && found < NSAMPLE; ++c) {
        int n = c * 64 + lane;
        float x = xb[n*3+0], y = xb[n*3+1], z = xb[n*3+2];
        float nsum = __fadd_rn(__fadd_rn(__fmul_rn(x,x), __fmul_rn(y,y)), __fmul_rn(z,z));
        float dot  = __fmaf_rn(s2, z, __fmaf_rn(s1, y, __fmul_rn(s0, x)));
        float d2   = __fsub_rn(__fadd_rn(ssum, nsum), __fmul_rn(2.0f, dot));
        bool inb = !(d2 > r2);
        unsigned long long m = __ballot(inb);
        if (first < 0 && m != 0ull) first = c * 64 + (int)__builtin_ctzll(m);
        if (inb) {
            int rank = __popcll(m & ((1ull << lane) - 1ull));
            int slot = found + rank;
            if (slot < NSAMPLE) myidx[slot] = n;
        }
        found += __popcll(m);
    }
    if (found > NSAMPLE) found = NSAMPLE;
    for (int slot = found + lane; slot < NSAMPLE; slot += 64) myidx[slot] = first;
}

// ---------------------------------------------------------------------------
// Kernel 3: gather + 3x (matmul, BN, ReLU) + max over the 32 samples.
// BN folded into weights/bias. Weights staged transposed in LDS, read as
// broadcast float4 (conflict-free). Lane = (s_local*32 + k): max-pool is a
// 32-lane shfl_xor reduce. One point per lane.
// ---------------------------------------------------------------------------
__global__ __launch_bounds__(256)
void mlp_kernel(const float* __restrict__ xyz, const float* __restrict__ points,
                const float* __restrict__ new_xyz, const int* __restrict__ idx,
                const float* __restrict__ W1, const float* __restrict__ g1,
                const float* __restrict__ b1, const float* __restrict__ m1,
                const float* __restrict__ v1,
                const float* __restrict__ W2, const float* __restrict__ g2,
                const float* __restrict__ b2, const float* __restrict__ m2,
                const float* __restrict__ v2,
                const float* __restrict__ W3, const float* __restrict__ g3,
                const float* __restrict__ b3, const float* __restrict__ m3,
                const float* __restrict__ v3,
                float* __restrict__ feat)
{
    __shared__ float w1t[64][8];     // [out][in(6, padded 8)]
    __shared__ float w2t[64][64];    // [out][in]
    __shared__ float w3t[128][64];   // [out][in]
    __shared__ float bias1s[64], bias2s[64], bias3s[128];
    __shared__ float sc1[64], sc2[64], sc3[128];

    const int tid = threadIdx.x;

    for (int d = tid; d < 64; d += 256) {
        float s1v = g1[d] / sqrtf(v1[d] + 1e-5f);
        sc1[d] = s1v; bias1s[d] = b1[d] - m1[d] * s1v;
        float s2v = g2[d] / sqrtf(v2[d] + 1e-5f);
        sc2[d] = s2v; bias2s[d] = b2[d] - m2[d] * s2v;
    }
    for (int d = tid; d < 128; d += 256) {
        float s3v = g3[d] / sqrtf(v3[d] + 1e-5f);
        sc3[d] = s3v; bias3s[d] = b3[d] - m3[d] * s3v;
    }
    __syncthreads();
    for (int e = tid; e < 64 * 8; e += 256) {
        int d = e >> 3, c = e & 7;
        w1t[d][c] = (c < 6) ? W1[c * 64 + d] * sc1[d] : 0.f;
    }
    for (int e = tid; e < 64 * 64; e += 256) {
        int d = e >> 6, c = e & 63;
        w2t[d][c] = W2[c * 64 + d] * sc2[d];
    }
    for (int e = tid; e < 128 * 64; e += 256) {
        int d = e >> 6, c = e & 63;
        w3t[d][c] = W3[c * 128 + d] * sc3[d];
    }
    __syncthreads();

    const int wid  = tid >> 6;
    const int lane = tid & 63;
    const int q = blockIdx.x * 8 + wid * 2 + (lane >> 5);
    const int k = lane & 31;
    const int b = q >> 10;

    const int n = idx[(size_t)q * NSAMPLE + k];
    const float* xp = xyz    + ((size_t)b * NPTS + n) * 3;
    const float* pp = points + ((size_t)b * NPTS + n) * 3;
    const float* nx = new_xyz + (size_t)q * 3;

    const float in0 = __fsub_rn(xp[0], nx[0]);
    const float in1 = __fsub_rn(xp[1], nx[1]);
    const float in2 = __fsub_rn(xp[2], nx[2]);
    const float in3 = pp[0], in4 = pp[1], in5 = pp[2];

    float x1[64];
#pragma unroll
    for (int d = 0; d < 64; ++d) {
        const float4 wa = *(const float4*)&w1t[d][0];
        const float4 wb = *(const float4*)&w1t[d][4];
        float acc = bias1s[d];
        acc = fmaf(in0, wa.x, acc);
        acc = fmaf(in1, wa.y, acc);
        acc = fmaf(in2, wa.z, acc);
        acc = fmaf(in3, wa.w, acc);
        acc = fmaf(in4, wb.x, acc);
        acc = fmaf(in5, wb.y, acc);
        x1[d] = fmaxf(acc, 0.f);
    }

    float x2[64];
#pragma unroll
    for (int d = 0; d < 64; ++d) {
        float acc = bias2s[d];
        const float4* wr = (const float4*)w2t[d];
#pragma unroll
        for (int cc = 0; cc < 16; ++cc) {
            float4 w = wr[cc];
            acc = fmaf(x1[4*cc+0], w.x, acc);
            acc = fmaf(x1[4*cc+1], w.y, acc);
            acc = fmaf(x1[4*cc+2], w.z, acc);
            acc = fmaf(x1[4*cc+3], w.w, acc);
        }
        x2[d] = fmaxf(acc, 0.f);
    }

    float* fq = feat + (size_t)q * 128;
    for (int d = 0; d < 128; ++d) {
        float acc = bias3s[d];
        const float4* wr = (const float4*)w3t[d];
#pragma unroll
        for (int cc = 0; cc < 16; ++cc) {
            float4 w = wr[cc];
            acc = fmaf(x2[4*cc+0], w.x, acc);
            acc = fmaf(x2[4*cc+1], w.y, acc);
            acc = fmaf(x2[4*cc+2], w.z, acc);
            acc = fmaf(x2[4*cc+3], w.w, acc);
        }
        float vv = fmaxf(acc, 0.f);
#pragma unroll
        for (int off = 16; off >= 1; off >>= 1)
            vv = fmaxf(vv, __shfl_xor(vv, off));
        if (k == 0) fq[d] = vv;
    }
}

extern "C" void kernel_launch(void* const* d_in, const int* in_sizes, int n_in,
                              void* d_out, int out_size, void* d_ws, size_t ws_size,
                              hipStream_t stream)
{
    (void)in_sizes; (void)n_in; (void)out_size; (void)ws_size;

    const float* xyz    = (const float*)d_in[0];
    const float* points = (const float*)d_in[1];
    const float* W1 = (const float*)d_in[2];
    const float* g1 = (const float*)d_in[3];
    const float* b1 = (const float*)d_in[4];
    const float* m1 = (const float*)d_in[5];
    const float* v1 = (const float*)d_in[6];
    const float* W2 = (const float*)d_in[7];
    const float* g2 = (const float*)d_in[8];
    const float* b2 = (const float*)d_in[9];
    const float* m2 = (const float*)d_in[10];
    const float* v2 = (const float*)d_in[11];
    const float* W3 = (const float*)d_in[12];
    const float* g3 = (const float*)d_in[13];
    const float* b3 = (const float*)d_in[14];
    const float* m3 = (const float*)d_in[15];
    const float* v3 = (const float*)d_in[16];

    float* out_f    = (float*)d_out;
    float* new_xyz  = out_f;                                  // B*NPOINT*3
    float* feat     = out_f + (size_t)BATCH * NPOINT * 3;     // B*NPOINT*128
    int*   idx      = (int*)d_ws;                             // B*NPOINT*NSAMPLE ints

    fps_kernel <<<BATCH, 256, 0, stream>>>(xyz, new_xyz);
    ball_kernel<<<(BATCH * NPOINT) / 4, 256, 0, stream>>>(xyz, new_xyz, idx);
    mlp_kernel <<<(BATCH * NPOINT) / 8, 256, 0, stream>>>(xyz, points, new_xyz, idx,
        W1, g1, b1, m1, v1, W2, g2, b2, m2, v2, W3, g3, b3, m3, v3, feat);
}

// Round 4
// 1041.841 us; speedup vs baseline: 2.0890x; 1.4097x over previous
//
#include <hip/hip_runtime.h>

#define BATCH   16
#define NPTS    4096
#define NPOINT  1024
#define NSAMPLE 32

// ---------------------------------------------------------------------------
// Kernel 1: farthest point sampling. One block per batch, 256 threads
// (4 waves), 16 points per thread held in REGISTERS (alias-defeating LDS
// write keeps the compiler from folding them back to LDS re-loads).
// Exact numpy fp32 op order: d = ((dx*dx+dy*dy)+dz*dz), dist=min(dist,d),
// argmax = first max (packed u64: hi=val bits, lo=~idx -> max = first-max).
// Reduction: 4x DPP row_ror rotation-reduce (VALU, rows of 16) ->
// 16 candidates -> double-buffered LDS post -> ONE barrier -> per-thread
// 8x ds_read_b128 broadcast + register tree.
// ---------------------------------------------------------------------------
__global__ __launch_bounds__(256)
void fps_kernel(const float* __restrict__ xyz, float* __restrict__ new_xyz)
{
    const int b    = blockIdx.x;
    const int t    = threadIdx.x;
    const int lane = t & 63;
    const int wv   = t >> 6;
    const float* xb = xyz + (size_t)b * NPTS * 3;

    __shared__ float sxyz[NPTS * 3];                       // 48 KB cloud copy
    __shared__ __align__(16) unsigned long long sCand[2][16];

    float px[16], py[16], pz[16], dist[16];
#pragma unroll
    for (int j = 0; j < 16; ++j) {
        const int n = j * 256 + t;
        const float X = xb[n * 3 + 0];
        const float Y = xb[n * 3 + 1];
        const float Z = xb[n * 3 + 2];
        px[j] = X; py[j] = Y; pz[j] = Z; dist[j] = 1e10f;
        sxyz[n * 3 + 0] = X; sxyz[n * 3 + 1] = Y; sxyz[n * 3 + 2] = Z;
    }
    __syncthreads();

    float cx = sxyz[0], cy = sxyz[1], cz = sxyz[2];        // first centroid = pt 0
    float* out = new_xyz + (size_t)b * NPOINT * 3;

    for (int i = 0; i < NPOINT; ++i) {
        if (t == 0) { out[i*3+0] = cx; out[i*3+1] = cy; out[i*3+2] = cz; }

        // update running min-distances; per-thread argmax (strict > + per-lane
        // ascending n over j == first occurrence)
        float bval = -1.0f; int bidx = 0;
#pragma unroll
        for (int j = 0; j < 16; ++j) {
            float dx = __fsub_rn(px[j], cx);
            float dy = __fsub_rn(py[j], cy);
            float dz = __fsub_rn(pz[j], cz);
            float d  = __fadd_rn(__fadd_rn(__fmul_rn(dx, dx), __fmul_rn(dy, dy)),
                                 __fmul_rn(dz, dz));
            float nd = fminf(dist[j], d);
            dist[j] = nd;
            if (nd > bval) { bval = nd; bidx = j * 256 + t; }
        }

        // pack: dist >= 0 so fp32 bits are order-isomorphic; ~idx makes
        // u64-max pick the SMALLEST index on val ties (numpy first-max).
        unsigned long long cand =
            ((unsigned long long)__float_as_uint(bval) << 32) |
            (unsigned long long)(unsigned int)~bidx;

        // 16-lane rotation-reduce via DPP row_ror:{1,2,4,8} (pure VALU)
#define DPP_RED(CTRL)                                                          \
        {                                                                      \
            unsigned int oh = (unsigned int)__builtin_amdgcn_update_dpp(       \
                0, (int)(unsigned int)(cand >> 32), (CTRL), 0xF, 0xF, true);   \
            unsigned int ol = (unsigned int)__builtin_amdgcn_update_dpp(       \
                0, (int)(unsigned int)cand, (CTRL), 0xF, 0xF, true);           \
            unsigned long long o =                                             \
                ((unsigned long long)oh << 32) | (unsigned long long)ol;       \
            if (o > cand) cand = o;                                            \
        }
        DPP_RED(0x121)   // row_ror:1
        DPP_RED(0x122)   // row_ror:2
        DPP_RED(0x124)   // row_ror:4
        DPP_RED(0x128)   // row_ror:8
#undef DPP_RED

        // 16 row-winners -> LDS (double-buffered), single barrier
        const int par = i & 1;
        if ((lane & 15) == 0) sCand[par][(wv << 2) | (lane >> 4)] = cand;
        __syncthreads();

        // every thread: broadcast-read all 16, register tree reduce
        unsigned long long c[16];
        const ulonglong2* pc = (const ulonglong2*)&sCand[par][0];
#pragma unroll
        for (int u = 0; u < 8; ++u) { ulonglong2 v2 = pc[u]; c[2*u] = v2.x; c[2*u+1] = v2.y; }
#pragma unroll
        for (int s = 8; s >= 1; s >>= 1)
#pragma unroll
            for (int u = 0; u < s; ++u)
                if (c[u + s] > c[u]) c[u] = c[u + s];
        const unsigned int ix = ~(unsigned int)c[0];

        // winner coords via LDS broadcast read
        cx = sxyz[ix * 3 + 0];
        cy = sxyz[ix * 3 + 1];
        cz = sxyz[ix * 3 + 2];
        // Benign same-value write with data-dependent index: defeats the
        // compiler's "sxyz never written in loop" proof so px/py/pz/dist stay
        // in VGPRs instead of being re-loaded from LDS every iteration.
        if (t == 0) sxyz[ix * 3 + 0] = cx;
    }
}

// ---------------------------------------------------------------------------
// Kernel 2: ball query. One wave per query point. Scans points in ascending
// index order, takes the first 32 with d2 <= r^2, pads with first in-ball idx.
// d2 arithmetic must match numpy: dot via SEQUENTIAL FMA (einsum inner loop
// contracts to fma), everything else separate _rn ops (distinct ufuncs).
// VALIDATED — do not change arithmetic.
// ---------------------------------------------------------------------------
__global__ __launch_bounds__(256)
void ball_kernel(const float* __restrict__ xyz, const float* __restrict__ new_xyz,
                 int* __restrict__ idx)
{
    const int q    = blockIdx.x * 4 + (threadIdx.x >> 6);
    const int lane = threadIdx.x & 63;
    const int b    = q >> 10;
    const float* xb = xyz + (size_t)b * NPTS * 3;

    const float s0 = new_xyz[q*3+0];
    const float s1 = new_xyz[q*3+1];
    const float s2 = new_xyz[q*3+2];
    const float ssum = __fadd_rn(__fadd_rn(__fmul_rn(s0,s0), __fmul_rn(s1,s1)),
                                 __fmul_rn(s2,s2));
    const float r2 = (float)(0.2 * 0.2);

    int* myidx = idx + (size_t)q * NSAMPLE;
    int found = 0;
    int first = -1;

    for (int c = 0; c < NPTS / 64 && found < NSAMPLE; ++c) {
        int n = c * 64 + lane;
        float x = xb[n*3+0], y = xb[n*3+1], z = xb[n*3+2];
        float nsum = __fadd_rn(__fadd_rn(__fmul_rn(x,x), __fmul_rn(y,y)), __fmul_rn(z,z));
        float dot  = __fmaf_rn(s2, z, __fmaf_rn(s1, y, __fmul_rn(s0, x)));
        float d2   = __fsub_rn(__fadd_rn(ssum, nsum), __fmul_rn(2.0f, dot));
        bool inb = !(d2 > r2);
        unsigned long long m = __ballot(inb);
        if (first < 0 && m != 0ull) first = c * 64 + (int)__builtin_ctzll(m);
        if (inb) {
            int rank = __popcll(m & ((1ull << lane) - 1ull));
            int slot = found + rank;
            if (slot < NSAMPLE) myidx[slot] = n;
        }
        found += __popcll(m);
    }
    if (found > NSAMPLE) found = NSAMPLE;
    for (int slot = found + lane; slot < NSAMPLE; slot += 64) myidx[slot] = first;
}

// ---------------------------------------------------------------------------
// Kernel 3: gather + 3x (matmul, BN, ReLU) + max over the 32 samples.
// BN folded into weights/bias. Weights staged transposed in LDS, read as
// broadcast float4 (conflict-free). Lane = (s_local*32 + k): max-pool is a
// 32-lane shfl_xor reduce. One point per lane.
// ---------------------------------------------------------------------------
__global__ __launch_bounds__(256)
void mlp_kernel(const float* __restrict__ xyz, const float* __restrict__ points,
                const float* __restrict__ new_xyz, const int* __restrict__ idx,
                const float* __restrict__ W1, const float* __restrict__ g1,
                const float* __restrict__ b1, const float* __restrict__ m1,
                const float* __restrict__ v1,
                const float* __restrict__ W2, const float* __restrict__ g2,
                const float* __restrict__ b2, const float* __restrict__ m2,
                const float* __restrict__ v2,
                const float* __restrict__ W3, const float* __restrict__ g3,
                const float* __restrict__ b3, const float* __restrict__ m3,
                const float* __restrict__ v3,
                float* __restrict__ feat)
{
    __shared__ float w1t[64][8];     // [out][in(6, padded 8)]
    __shared__ float w2t[64][64];    // [out][in]
    __shared__ float w3t[128][64];   // [out][in]
    __shared__ float bias1s[64], bias2s[64], bias3s[128];
    __shared__ float sc1[64], sc2[64], sc3[128];

    const int tid = threadIdx.x;

    for (int d = tid; d < 64; d += 256) {
        float s1v = g1[d] / sqrtf(v1[d] + 1e-5f);
        sc1[d] = s1v; bias1s[d] = b1[d] - m1[d] * s1v;
        float s2v = g2[d] / sqrtf(v2[d] + 1e-5f);
        sc2[d] = s2v; bias2s[d] = b2[d] - m2[d] * s2v;
    }
    for (int d = tid; d < 128; d += 256) {
        float s3v = g3[d] / sqrtf(v3[d] + 1e-5f);
        sc3[d] = s3v; bias3s[d] = b3[d] - m3[d] * s3v;
    }
    __syncthreads();
    for (int e = tid; e < 64 * 8; e += 256) {
        int d = e >> 3, c = e & 7;
        w1t[d][c] = (c < 6) ? W1[c * 64 + d] * sc1[d] : 0.f;
    }
    for (int e = tid; e < 64 * 64; e += 256) {
        int d = e >> 6, c = e & 63;
        w2t[d][c] = W2[c * 64 + d] * sc2[d];
    }
    for (int e = tid; e < 128 * 64; e += 256) {
        int d = e >> 6, c = e & 63;
        w3t[d][c] = W3[c * 128 + d] * sc3[d];
    }
    __syncthreads();

    const int wid  = tid >> 6;
    const int lane = tid & 63;
    const int q = blockIdx.x * 8 + wid * 2 + (lane >> 5);
    const int k = lane & 31;
    const int b = q >> 10;

    const int n = idx[(size_t)q * NSAMPLE + k];
    const float* xp = xyz    + ((size_t)b * NPTS + n) * 3;
    const float* pp = points + ((size_t)b * NPTS + n) * 3;
    const float* nx = new_xyz + (size_t)q * 3;

    const float in0 = __fsub_rn(xp[0], nx[0]);
    const float in1 = __fsub_rn(xp[1], nx[1]);
    const float in2 = __fsub_rn(xp[2], nx[2]);
    const float in3 = pp[0], in4 = pp[1], in5 = pp[2];

    float x1[64];
#pragma unroll
    for (int d = 0; d < 64; ++d) {
        const float4 wa = *(const float4*)&w1t[d][0];
        const float4 wb = *(const float4*)&w1t[d][4];
        float acc = bias1s[d];
        acc = fmaf(in0, wa.x, acc);
        acc = fmaf(in1, wa.y, acc);
        acc = fmaf(in2, wa.z, acc);
        acc = fmaf(in3, wa.w, acc);
        acc = fmaf(in4, wb.x, acc);
        acc = fmaf(in5, wb.y, acc);
        x1[d] = fmaxf(acc, 0.f);
    }

    float x2[64];
#pragma unroll
    for (int d = 0; d < 64; ++d) {
        float acc = bias2s[d];
        const float4* wr = (const float4*)w2t[d];
#pragma unroll
        for (int cc = 0; cc < 16; ++cc) {
            float4 w = wr[cc];
            acc = fmaf(x1[4*cc+0], w.x, acc);
            acc = fmaf(x1[4*cc+1], w.y, acc);
            acc = fmaf(x1[4*cc+2], w.z, acc);
            acc = fmaf(x1[4*cc+3], w.w, acc);
        }
        x2[d] = fmaxf(acc, 0.f);
    }

    float* fq = feat + (size_t)q * 128;
    for (int d = 0; d < 128; ++d) {
        float acc = bias3s[d];
        const float4* wr = (const float4*)w3t[d];
#pragma unroll
        for (int cc = 0; cc < 16; ++cc) {
            float4 w = wr[cc];
            acc = fmaf(x2[4*cc+0], w.x, acc);
            acc = fmaf(x2[4*cc+1], w.y, acc);
            acc = fmaf(x2[4*cc+2], w.z, acc);
            acc = fmaf(x2[4*cc+3], w.w, acc);
        }
        float vv = fmaxf(acc, 0.f);
#pragma unroll
        for (int off = 16; off >= 1; off >>= 1)
            vv = fmaxf(vv, __shfl_xor(vv, off));
        if (k == 0) fq[d] = vv;
    }
}

extern "C" void kernel_launch(void* const* d_in, const int* in_sizes, int n_in,
                              void* d_out, int out_size, void* d_ws, size_t ws_size,
                              hipStream_t stream)
{
    (void)in_sizes; (void)n_in; (void)out_size; (void)ws_size;

    const float* xyz    = (const float*)d_in[0];
    const float* points = (const float*)d_in[1];
    const float* W1 = (const float*)d_in[2];
    const float* g1 = (const float*)d_in[3];
    const float* b1 = (const float*)d_in[4];
    const float* m1 = (const float*)d_in[5];
    const float* v1 = (const float*)d_in[6];
    const float* W2 = (const float*)d_in[7];
    const float* g2 = (const float*)d_in[8];
    const float* b2 = (const float*)d_in[9];
    const float* m2 = (const float*)d_in[10];
    const float* v2 = (const float*)d_in[11];
    const float* W3 = (const float*)d_in[12];
    const float* g3 = (const float*)d_in[13];
    const float* b3 = (const float*)d_in[14];
    const float* m3 = (const float*)d_in[15];
    const float* v3 = (const float*)d_in[16];

    float* out_f    = (float*)d_out;
    float* new_xyz  = out_f;                                  // B*NPOINT*3
    float* feat     = out_f + (size_t)BATCH * NPOINT * 3;     // B*NPOINT*128
    int*   idx      = (int*)d_ws;                             // B*NPOINT*NSAMPLE ints

    fps_kernel <<<BATCH, 256, 0, stream>>>(xyz, new_xyz);
    ball_kernel<<<(BATCH * NPOINT) / 4, 256, 0, stream>>>(xyz, new_xyz, idx);
    mlp_kernel <<<(BATCH * NPOINT) / 8, 256, 0, stream>>>(xyz, points, new_xyz, idx,
        W1, g1, b1, m1, v1, W2, g2, b2, m2, v2, W3, g3, b3, m3, v3, feat);
}

// Round 5
// 944.686 us; speedup vs baseline: 2.3038x; 1.1028x over previous
//
#include <hip/hip_runtime.h>

#define BATCH   16
#define NPTS    4096
#define NPOINT  1024
#define NSAMPLE 32

// ---------------------------------------------------------------------------
// Kernel 1: farthest point sampling. One block per batch, 256 threads
// (4 waves), 16 points per thread held in REGISTERS — pinned with an asm
// barrier so the compiler cannot rematerialize them from global memory
// (round-4 lesson: VGPR=68 proved it was re-loading 48 values from L2 every
// one of the 1024 serial iterations).
// Exact numpy fp32 op order: d = ((dx*dx+dy*dy)+dz*dz), dist=min(dist,d),
// argmax = first max (packed u64: hi=val bits, lo=~idx -> u64 max = first-max).
// Reduction: 6 DPP rounds (row_ror 1/2/4/8 + row_bcast15 + row_bcast31),
// lane 63 posts the wave winner -> 4 slots, double-buffered, ONE barrier ->
// 2x ds_read_b128 + 3-compare u64 tree -> coords via LDS broadcast read.
// ---------------------------------------------------------------------------
__global__ __launch_bounds__(256)
void fps_kernel(const float* __restrict__ xyz, float* __restrict__ new_xyz)
{
    const int b    = blockIdx.x;
    const int t    = threadIdx.x;
    const int lane = t & 63;
    const int wv   = t >> 6;
    const float* xb = xyz + (size_t)b * NPTS * 3;

    __shared__ float sxyz[NPTS * 3];                       // 48 KB cloud copy
    __shared__ __align__(16) unsigned long long sCand[2][4];

    float px[16], py[16], pz[16], dist[16];
#pragma unroll
    for (int j = 0; j < 16; ++j) {
        const int n = j * 256 + t;
        float X = xb[n * 3 + 0];
        float Y = xb[n * 3 + 1];
        float Z = xb[n * 3 + 2];
        sxyz[n * 3 + 0] = X; sxyz[n * 3 + 1] = Y; sxyz[n * 3 + 2] = Z;
        // Pin to VGPRs: value becomes asm-defined, so the compiler cannot
        // rematerialize it from xb (global) or sxyz (LDS) inside the loop.
        asm volatile("" : "+v"(X), "+v"(Y), "+v"(Z));
        px[j] = X; py[j] = Y; pz[j] = Z; dist[j] = 1e10f;
    }
    __syncthreads();

    float cx = sxyz[0], cy = sxyz[1], cz = sxyz[2];        // first centroid = pt 0
    float* out = new_xyz + (size_t)b * NPOINT * 3;

    for (int i = 0; i < NPOINT; ++i) {
        if (t == 0) { out[i*3+0] = cx; out[i*3+1] = cy; out[i*3+2] = cz; }

        // update running min-distances; per-thread argmax (strict > + per-lane
        // ascending n over j == first occurrence)
        float bval = -1.0f; int bidx = 0;
#pragma unroll
        for (int j = 0; j < 16; ++j) {
            float dx = __fsub_rn(px[j], cx);
            float dy = __fsub_rn(py[j], cy);
            float dz = __fsub_rn(pz[j], cz);
            float d  = __fadd_rn(__fadd_rn(__fmul_rn(dx, dx), __fmul_rn(dy, dy)),
                                 __fmul_rn(dz, dz));
            float nd = fminf(dist[j], d);
            dist[j] = nd;
            if (nd > bval) { bval = nd; bidx = j * 256 + t; }
        }

        // pack: dist >= 0 (bval set on j=0 since nd >= 0 > -1), so fp32 bits
        // are order-isomorphic; ~idx makes u64-max pick the SMALLEST index on
        // val ties (numpy first-max).
        unsigned long long cand =
            ((unsigned long long)__float_as_uint(bval) << 32) |
            (unsigned long long)(unsigned int)~bidx;

        // full-wave reduce, pure VALU DPP:
        //   4x row_ror  -> every lane holds its 16-lane row max
        //   row_bcast15 (rows 1,3) + row_bcast31 (rows 2,3) -> lane 63 = wave max
#define DPP_RED(CTRL, RMASK)                                                   \
        {                                                                      \
            unsigned int oh = (unsigned int)__builtin_amdgcn_update_dpp(       \
                0, (int)(unsigned int)(cand >> 32), (CTRL), (RMASK), 0xF, true);\
            unsigned int ol = (unsigned int)__builtin_amdgcn_update_dpp(       \
                0, (int)(unsigned int)cand, (CTRL), (RMASK), 0xF, true);       \
            unsigned long long o =                                             \
                ((unsigned long long)oh << 32) | (unsigned long long)ol;       \
            if (o > cand) cand = o;                                            \
        }
        DPP_RED(0x121, 0xF)   // row_ror:1
        DPP_RED(0x122, 0xF)   // row_ror:2
        DPP_RED(0x124, 0xF)   // row_ror:4
        DPP_RED(0x128, 0xF)   // row_ror:8
        DPP_RED(0x142, 0xA)   // row_bcast15 -> rows 1,3
        DPP_RED(0x143, 0xC)   // row_bcast31 -> rows 2,3
#undef DPP_RED

        // 4 wave-winners -> LDS (double-buffered), single barrier
        const int par = i & 1;
        if (lane == 63) sCand[par][wv] = cand;
        __syncthreads();

        // every thread: 2x ds_read_b128 broadcast + 3-compare u64 tree
        const ulonglong2* pc = (const ulonglong2*)&sCand[par][0];
        ulonglong2 r0 = pc[0], r1 = pc[1];
        unsigned long long m01 = (r0.y > r0.x) ? r0.y : r0.x;
        unsigned long long m23 = (r1.y > r1.x) ? r1.y : r1.x;
        unsigned long long m   = (m23 > m01) ? m23 : m01;
        const unsigned int ix = ~(unsigned int)m;

        // winner coords via LDS broadcast read
        cx = sxyz[ix * 3 + 0];
        cy = sxyz[ix * 3 + 1];
        cz = sxyz[ix * 3 + 2];
    }
}

// ---------------------------------------------------------------------------
// Kernel 2: ball query. One wave per query point. Scans points in ascending
// index order, takes the first 32 with d2 <= r^2, pads with first in-ball idx.
// d2 arithmetic must match numpy: dot via SEQUENTIAL FMA (einsum inner loop
// contracts to fma), everything else separate _rn ops (distinct ufuncs).
// VALIDATED — do not change arithmetic.
// ---------------------------------------------------------------------------
__global__ __launch_bounds__(256)
void ball_kernel(const float* __restrict__ xyz, const float* __restrict__ new_xyz,
                 int* __restrict__ idx)
{
    const int q    = blockIdx.x * 4 + (threadIdx.x >> 6);
    const int lane = threadIdx.x & 63;
    const int b    = q >> 10;
    const float* xb = xyz + (size_t)b * NPTS * 3;

    const float s0 = new_xyz[q*3+0];
    const float s1 = new_xyz[q*3+1];
    const float s2 = new_xyz[q*3+2];
    const float ssum = __fadd_rn(__fadd_rn(__fmul_rn(s0,s0), __fmul_rn(s1,s1)),
                                 __fmul_rn(s2,s2));
    const float r2 = (float)(0.2 * 0.2);

    int* myidx = idx + (size_t)q * NSAMPLE;
    int found = 0;
    int first = -1;

    for (int c = 0; c < NPTS / 64 && found < NSAMPLE; ++c) {
        int n = c * 64 + lane;
        float x = xb[n*3+0], y = xb[n*3+1], z = xb[n*3+2];
        float nsum = __fadd_rn(__fadd_rn(__fmul_rn(x,x), __fmul_rn(y,y)), __fmul_rn(z,z));
        float dot  = __fmaf_rn(s2, z, __fmaf_rn(s1, y, __fmul_rn(s0, x)));
        float d2   = __fsub_rn(__fadd_rn(ssum, nsum), __fmul_rn(2.0f, dot));
        bool inb = !(d2 > r2);
        unsigned long long m = __ballot(inb);
        if (first < 0 && m != 0ull) first = c * 64 + (int)__builtin_ctzll(m);
        if (inb) {
            int rank = __popcll(m & ((1ull << lane) - 1ull));
            int slot = found + rank;
            if (slot < NSAMPLE) myidx[slot] = n;
        }
        found += __popcll(m);
    }
    if (found > NSAMPLE) found = NSAMPLE;
    for (int slot = found + lane; slot < NSAMPLE; slot += 64) myidx[slot] = first;
}

// ---------------------------------------------------------------------------
// Kernel 3: gather + 3x (matmul, BN, ReLU) + max over the 32 samples.
// BN folded into weights/bias. Weights staged transposed in LDS, read as
// broadcast float4 (conflict-free). Lane = (s_local*32 + k): max-pool is a
// 32-lane shfl_xor reduce. One point per lane.
// ---------------------------------------------------------------------------
__global__ __launch_bounds__(256)
void mlp_kernel(const float* __restrict__ xyz, const float* __restrict__ points,
                const float* __restrict__ new_xyz, const int* __restrict__ idx,
                const float* __restrict__ W1, const float* __restrict__ g1,
                const float* __restrict__ b1, const float* __restrict__ m1,
                const float* __restrict__ v1,
                const float* __restrict__ W2, const float* __restrict__ g2,
                const float* __restrict__ b2, const float* __restrict__ m2,
                const float* __restrict__ v2,
                const float* __restrict__ W3, const float* __restrict__ g3,
                const float* __restrict__ b3, const float* __restrict__ m3,
                const float* __restrict__ v3,
                float* __restrict__ feat)
{
    __shared__ float w1t[64][8];     // [out][in(6, padded 8)]
    __shared__ float w2t[64][64];    // [out][in]
    __shared__ float w3t[128][64];   // [out][in]
    __shared__ float bias1s[64], bias2s[64], bias3s[128];
    __shared__ float sc1[64], sc2[64], sc3[128];

    const int tid = threadIdx.x;

    for (int d = tid; d < 64; d += 256) {
        float s1v = g1[d] / sqrtf(v1[d] + 1e-5f);
        sc1[d] = s1v; bias1s[d] = b1[d] - m1[d] * s1v;
        float s2v = g2[d] / sqrtf(v2[d] + 1e-5f);
        sc2[d] = s2v; bias2s[d] = b2[d] - m2[d] * s2v;
    }
    for (int d = tid; d < 128; d += 256) {
        float s3v = g3[d] / sqrtf(v3[d] + 1e-5f);
        sc3[d] = s3v; bias3s[d] = b3[d] - m3[d] * s3v;
    }
    __syncthreads();
    for (int e = tid; e < 64 * 8; e += 256) {
        int d = e >> 3, c = e & 7;
        w1t[d][c] = (c < 6) ? W1[c * 64 + d] * sc1[d] : 0.f;
    }
    for (int e = tid; e < 64 * 64; e += 256) {
        int d = e >> 6, c = e & 63;
        w2t[d][c] = W2[c * 64 + d] * sc2[d];
    }
    for (int e = tid; e < 128 * 64; e += 256) {
        int d = e >> 6, c = e & 63;
        w3t[d][c] = W3[c * 128 + d] * sc3[d];
    }
    __syncthreads();

    const int wid  = tid >> 6;
    const int lane = tid & 63;
    const int q = blockIdx.x * 8 + wid * 2 + (lane >> 5);
    const int k = lane & 31;
    const int b = q >> 10;

    const int n = idx[(size_t)q * NSAMPLE + k];
    const float* xp = xyz    + ((size_t)b * NPTS + n) * 3;
    const float* pp = points + ((size_t)b * NPTS + n) * 3;
    const float* nx = new_xyz + (size_t)q * 3;

    const float in0 = __fsub_rn(xp[0], nx[0]);
    const float in1 = __fsub_rn(xp[1], nx[1]);
    const float in2 = __fsub_rn(xp[2], nx[2]);
    const float in3 = pp[0], in4 = pp[1], in5 = pp[2];

    float x1[64];
#pragma unroll
    for (int d = 0; d < 64; ++d) {
        const float4 wa = *(const float4*)&w1t[d][0];
        const float4 wb = *(const float4*)&w1t[d][4];
        float acc = bias1s[d];
        acc = fmaf(in0, wa.x, acc);
        acc = fmaf(in1, wa.y, acc);
        acc = fmaf(in2, wa.z, acc);
        acc = fmaf(in3, wa.w, acc);
        acc = fmaf(in4, wb.x, acc);
        acc = fmaf(in5, wb.y, acc);
        x1[d] = fmaxf(acc, 0.f);
    }

    float x2[64];
#pragma unroll
    for (int d = 0; d < 64; ++d) {
        float acc = bias2s[d];
        const float4* wr = (const float4*)w2t[d];
#pragma unroll
        for (int cc = 0; cc < 16; ++cc) {
            float4 w = wr[cc];
            acc = fmaf(x1[4*cc+0], w.x, acc);
            acc = fmaf(x1[4*cc+1], w.y, acc);
            acc = fmaf(x1[4*cc+2], w.z, acc);
            acc = fmaf(x1[4*cc+3], w.w, acc);
        }
        x2[d] = fmaxf(acc, 0.f);
    }

    float* fq = feat + (size_t)q * 128;
    for (int d = 0; d < 128; ++d) {
        float acc = bias3s[d];
        const float4* wr = (const float4*)w3t[d];
#pragma unroll
        for (int cc = 0; cc < 16; ++cc) {
            float4 w = wr[cc];
            acc = fmaf(x2[4*cc+0], w.x, acc);
            acc = fmaf(x2[4*cc+1], w.y, acc);
            acc = fmaf(x2[4*cc+2], w.z, acc);
            acc = fmaf(x2[4*cc+3], w.w, acc);
        }
        float vv = fmaxf(acc, 0.f);
#pragma unroll
        for (int off = 16; off >= 1; off >>= 1)
            vv = fmaxf(vv, __shfl_xor(vv, off));
        if (k == 0) fq[d] = vv;
    }
}

extern "C" void kernel_launch(void* const* d_in, const int* in_sizes, int n_in,
                              void* d_out, int out_size, void* d_ws, size_t ws_size,
                              hipStream_t stream)
{
    (void)in_sizes; (void)n_in; (void)out_size; (void)ws_size;

    const float* xyz    = (const float*)d_in[0];
    const float* points = (const float*)d_in[1];
    const float* W1 = (const float*)d_in[2];
    const float* g1 = (const float*)d_in[3];
    const float* b1 = (const float*)d_in[4];
    const float* m1 = (const float*)d_in[5];
    const float* v1 = (const float*)d_in[6];
    const float* W2 = (const float*)d_in[7];
    const float* g2 = (const float*)d_in[8];
    const float* b2 = (const float*)d_in[9];
    const float* m2 = (const float*)d_in[10];
    const float* v2 = (const float*)d_in[11];
    const float* W3 = (const float*)d_in[12];
    const float* g3 = (const float*)d_in[13];
    const float* b3 = (const float*)d_in[14];
    const float* m3 = (const float*)d_in[15];
    const float* v3 = (const float*)d_in[16];

    float* out_f    = (float*)d_out;
    float* new_xyz  = out_f;                                  // B*NPOINT*3
    float* feat     = out_f + (size_t)BATCH * NPOINT * 3;     // B*NPOINT*128
    int*   idx      = (int*)d_ws;                             // B*NPOINT*NSAMPLE ints

    fps_kernel <<<BATCH, 256, 0, stream>>>(xyz, new_xyz);
    ball_kernel<<<(BATCH * NPOINT) / 4, 256, 0, stream>>>(xyz, new_xyz, idx);
    mlp_kernel <<<(BATCH * NPOINT) / 8, 256, 0, stream>>>(xyz, points, new_xyz, idx,
        W1, g1, b1, m1, v1, W2, g2, b2, m2, v2, W3, g3, b3, m3, v3, feat);
}